// Round 14
// baseline (1602.348 us; speedup 1.0000x reference)
//
#include <hip/hip_runtime.h>
#include <hip/hip_fp16.h>
#include <stdint.h>
#include <math.h>

typedef unsigned int uint;
typedef unsigned short ushort;
typedef unsigned long long ull;
typedef __attribute__((ext_vector_type(8))) _Float16 f16x8;
typedef __attribute__((ext_vector_type(4))) float f32x4;

#define BATCH 2
#define ATOTAL 242991
#define KSEL 4741
#define NW 75
#define POST_NMS 1000
#define WB_ELEMS (2*8*3*3*2*8*64*8)   // 1,179,648 u16 = 2.25 MB
#define NPAIRS 2850                   // 75*76/2 upper-triangle block pairs

// runtime-indexed device copies
__device__ __constant__ int dLoff[5]  = {0,182400,228000,239400,242250};
__device__ __constant__ int dCount[5] = {182400,45600,11400,2850,741};
__device__ __constant__ int dSeg[5]   = {0,1000,2000,3000,4000};
__device__ __constant__ int dSegK[5]  = {1000,1000,1000,1000,741};
__device__ __constant__ int dHc[5]     = {200,100,50,25,13};
__device__ __constant__ int dWc[5]     = {304,152,76,38,19};
__device__ __constant__ int dTilesX[5] = {19,10,5,3,2};
__device__ __constant__ int dCumT[6]   = {0,475,605,640,652,656};   // 8x16 tiles
__device__ __constant__ int dStrideC[5]= {4,8,16,32,64};
__device__ __constant__ int dSizeC[5]  = {32,64,128,256,512};

__device__ __forceinline__ uint fkey(float f) {
    uint u = __float_as_uint(f);
    return (u & 0x80000000u) ? ~u : (u | 0x80000000u);
}
__device__ __forceinline__ ushort h2u(__half h) {
    union { __half h; ushort u; } x; x.h = h; return x.u;
}

// ---------------- weight gen: conv_w -> wB fp16 (h, m*1024), slab-contiguous per (ocg,icblk,dy) ----
// layout: [ocg2][icblk8][dy3][dx3][pl2][nt8][lane64][e8] u16  (one (ocg,icblk,dy) slab = 24576 u16)
__global__ __launch_bounds__(256) void wt_kernel(const float* __restrict__ conv_w,
                                                 ushort* __restrict__ wB) {
    int t = blockIdx.x * 256 + threadIdx.x;
    if (t >= WB_ELEMS) return;
    int e    = t & 7;
    int lane = (t >> 3) & 63;
    int nt   = (t >> 9) & 7;
    int pl   = (t >> 12) & 1;
    int r    = t >> 13;            // dx + 3*(dy + 3*(icblk + 8*ocg))
    int dx = r % 3; r /= 3;
    int dy = r % 3; r /= 3;
    int icblk = r & 7;
    int ocg = r >> 3;
    int oc = ocg * 128 + nt * 16 + (lane & 15);
    int ic = icblk * 32 + ((lane >> 4) << 3) + e;
    float v = conv_w[(size_t)oc * 2304 + ic * 9 + dy * 3 + dx];
    __half h = __float2half(v);
    float rr = (v - __half2float(h)) * 1024.0f;   // scaled residual stays fp16-normal
    __half m = __float2half(rr);
    wB[t] = (pl == 0) ? h2u(h) : h2u(m);
}

// ---------------- MFMA conv3x3 (fp16x2 scaled-m split) + f64 heads/decode ----
// Round-14: r11 config (best: 863us, 8x16 tile, 2x4 acc, no setprio, no spill) +
// DOUBLE-BUFFERED B slabs -> 1 barrier/step (was 2). Slab write happens AFTER compute
// (regs loaded one full step earlier -> vmcnt covered); barrier count 48->33 per ocg.
// Math order (icblk,dy,dx ascending per accumulator) bit-identical.
__global__ __launch_bounds__(512) void conv_mfma_all(
    const float* __restrict__ f0, const float* __restrict__ f1,
    const float* __restrict__ f2, const float* __restrict__ f3,
    const float* __restrict__ f4, const ushort* __restrict__ wB,
    const float* __restrict__ conv_b,
    const float* __restrict__ cls_w, const float* __restrict__ cls_b,
    const float* __restrict__ box_w, const float* __restrict__ box_b,
    float* __restrict__ scoresA, float* __restrict__ boxesA)
{
    const int bidx = blockIdx.x;
    const int b    = blockIdx.y;
    const int tid  = threadIdx.x;

    int lvl = 0;
#pragma unroll
    for (int l = 1; l < 5; ++l) if (bidx >= dCumT[l]) lvl = l;
    const int tile   = bidx - dCumT[lvl];
    const int H      = dHc[lvl], W = dWc[lvl];
    const int TILESX = dTilesX[lvl];
    const int ty0    = (tile / TILESX) * 8;
    const int tx0    = (tile % TILESX) * 16;
    const int HW     = H * W;
    const float* feat = (lvl == 0) ? f0 : (lvl == 1) ? f1 : (lvl == 2) ? f2 : (lvl == 3) ? f3 : f4;
    const float* fb = feat + (size_t)b * 256 * HW;

    __shared__ __align__(16) char uni[121344];
    ushort* halo  = (ushort*)uni;                 // [2pl][5760] u16 = 23040 B
    ushort* ldsB0 = (ushort*)(uni + 23040);       // 49152 B
    ushort* ldsB1 = (ushort*)(uni + 72192);       // 49152 B
    float*  tS    = (float*)uni;                  // 32768 B (aliases halo+B0 head, conv done)
    float*  hw2   = (float*)(uni + 32768);        // 4096 B (inside B0 region, conv done)
    double* houtD = (double*)uni;                 // 16384 B (aliases tS)

    const int lane = tid & 63, wave = tid >> 6;
    const int wm = wave >> 1, wn = wave & 1;
    const int g = lane >> 4, col = lane & 15;
    const int laneA = g * 1440 + col * 8;        // u16 idx, lane-constant part

    // halo staging coords (icblk-invariant): 5760 elems / 512 threads = 12 slots
    int  hdst[12]; int hoff[12]; bool hval[12];
#pragma unroll
    for (int j = 0; j < 12; ++j) {
        int e = tid + j * 512;
        hdst[j] = -1; hoff[j] = 0; hval[j] = false;
        if (e < 5760) {
            int ic = e / 180, rem = e - ic * 180;
            int hrow = rem / 18, hcol = rem - hrow * 18;
            int gy = ty0 + hrow - 1, gx = tx0 + hcol - 1;
            hdst[j] = (((ic >> 3) * 10 + hrow) * 18 + hcol) * 8 + (ic & 7);
            if (gy >= 0 && gy < H && gx >= 0 && gx < W) {
                hval[j] = true; hoff[j] = ic * HW + gy * W + gx;
            }
        }
    }

    double hacc[4] = {0,0,0,0};   // per-thread f64 head accumulators (4 heads)

    uint4 Br0, Br1, Br2, Br3, Br4, Br5;  // B slab prefetch regs (48 KB/block)

    auto loadB = [&](int gstep) {
        const uint4* gq = (const uint4*)(wB + (size_t)gstep * 24576);
        Br0 = gq[tid];        Br1 = gq[tid + 512];
        Br2 = gq[tid + 1024]; Br3 = gq[tid + 1536];
        Br4 = gq[tid + 2048]; Br5 = gq[tid + 2560];
    };
    auto writeB = [&](ushort* dst) {
        uint4* lq = (uint4*)dst;
        lq[tid] = Br0;         lq[tid + 512]  = Br1;
        lq[tid + 1024] = Br2;  lq[tid + 1536] = Br3;
        lq[tid + 2048] = Br4;  lq[tid + 2560] = Br5;
    };
    auto stageHalo = [&](int icb) {
        float hv[12];
        const float* fcb = fb + (size_t)icb * 32 * HW;
#pragma unroll
        for (int j = 0; j < 12; ++j)
            hv[j] = hval[j] ? fcb[hoff[j]] : 0.f;
#pragma unroll
        for (int j = 0; j < 12; ++j) {
            if (hdst[j] >= 0) {
                float v = hv[j];
                __half h = __float2half(v);
                float rr = (v - __half2float(h)) * 1024.0f;
                __half m = __float2half(rr);
                int li = hdst[j];
                halo[li] = h2u(h); halo[5760 + li] = h2u(m);
            }
        }
    };

#pragma unroll 1
    for (int ocg = 0; ocg < 2; ++ocg) {
        f32x4 accH[2][4], accM[2][4];
#pragma unroll
        for (int mi = 0; mi < 2; ++mi)
#pragma unroll
            for (int ni = 0; ni < 4; ++ni) {
                accH[mi][ni] = (f32x4){0.f, 0.f, 0.f, 0.f};
                accM[mi][ni] = (f32x4){0.f, 0.f, 0.f, 0.f};
            }

        // ---- prologue: halo icblk0 + slab0 into ldsB0 ----
        __syncthreads();               // prior phase's reads done
        stageHalo(0);
        loadB(ocg * 24);
        writeB(ldsB0);                 // waits vmcnt; once per ocg
        __syncthreads();               // halo + slab0 visible
        loadB(ocg * 24 + 1);           // prefetch slab1
        int cur = 0;

#pragma unroll 1
        for (int s = 0; s < 24; ++s) {
            const int icblk = s / 3;
            const int dy    = s - icblk * 3;
            ushort* Bcur = cur ? ldsB1 : ldsB0;

            // ---- compute: 3 dx sub-steps, 2mi x 4ni x 3 products each ----
#pragma unroll 1
            for (int dx = 0; dx < 3; ++dx) {
                f16x8 Ah[2], Am[2];
                const int abase = laneA + dx * 8 + (2 * wm + dy) * 144;
#pragma unroll
                for (int mi = 0; mi < 2; ++mi) {
                    Ah[mi] = *(const f16x8*)(halo + abase + mi * 144);
                    Am[mi] = *(const f16x8*)(halo + 5760 + abase + mi * 144);
                }
#pragma unroll
                for (int ni = 0; ni < 4; ++ni) {
                    const int nt = 4 * wn + ni;
                    f16x8 Bh = *(const f16x8*)(Bcur + (size_t)(dx * 16 + nt) * 512 + lane * 8);
                    f16x8 Bm = *(const f16x8*)(Bcur + (size_t)(dx * 16 + 8 + nt) * 512 + lane * 8);
#pragma unroll
                    for (int mi = 0; mi < 2; ++mi) {
                        f32x4 cH = accH[mi][ni];
                        f32x4 cM = accM[mi][ni];
                        cH = __builtin_amdgcn_mfma_f32_16x16x32_f16(Ah[mi], Bh, cH, 0, 0, 0);
                        cM = __builtin_amdgcn_mfma_f32_16x16x32_f16(Ah[mi], Bm, cM, 0, 0, 0);
                        cM = __builtin_amdgcn_mfma_f32_16x16x32_f16(Am[mi], Bh, cM, 0, 0, 0);
                        accH[mi][ni] = cH;
                        accM[mi][ni] = cM;
                    }
                }
            }
            // ---- write next slab (regs one step old -> latency covered) ----
            if (s < 23) writeB(cur ? ldsB0 : ldsB1);
            // ---- barrier(s); halo restage on icblk boundary ----
            if (s < 23 && ((s + 1) % 3 == 0)) {
                __syncthreads();       // all halo/Bcur reads done; next-slab writes visible
                stageHalo(icblk + 1);
                __syncthreads();       // new halo visible
            } else {
                __syncthreads();       // next-slab visible; Bcur reads done
            }
            if (s < 22) loadB(ocg * 24 + s + 2);
            cur ^= 1;
        }
        // ---- writeout + f64 head contraction, 2 slabs of 64 oc (oc ascending) ----
        float cb[4];
#pragma unroll
        for (int ni = 0; ni < 4; ++ni)
            cb[ni] = conv_b[ocg * 128 + (4 * wn + ni) * 16 + col];

#pragma unroll 1
        for (int s2 = 0; s2 < 2; ++s2) {
            if (wn == s2) {
#pragma unroll
                for (int mi = 0; mi < 2; ++mi) {
#pragma unroll
                    for (int r = 0; r < 4; ++r) {
                        int px = (2 * wm + mi) * 16 + 4 * g + r;
                        int sw = px & 15;
#pragma unroll
                        for (int ni = 0; ni < 4; ++ni) {
                            int slot = (ni * 4 + (col >> 2)) ^ sw;
                            float val = accH[mi][ni][r] + accM[mi][ni][r] * 0.0009765625f;
                            tS[px * 64 + slot * 4 + (col & 3)] =
                                fmaxf(val + cb[ni], 0.f);
                        }
                    }
                }
            }
            // stage head weights for this 64-oc slab (threads 0..255)
            if (tid < 256) {
                const int oc2 = tid >> 2;
                const int h0  = (tid & 3) * 4;
                const int oc  = ocg * 128 + s2 * 64 + oc2;
                float vv[4];
#pragma unroll
                for (int q = 0; q < 4; ++q) {
                    int h = h0 + q;
                    vv[q] = (h < 3) ? cls_w[h * 256 + oc]
                          : (h < 15) ? box_w[(h - 3) * 256 + oc] : 0.f;
                }
                *(float4*)&hw2[oc2 * 16 + h0] = make_float4(vv[0], vv[1], vv[2], vv[3]);
            }
            __syncthreads();
            // accumulate: px = tid&127, head-quarter = tid>>7 (oc ascending within slab)
            {
                const int px = tid & 127;
                const int hh = tid >> 7;           // 0..3, heads hh*4..hh*4+3
                const int sw = px & 15;
#pragma unroll 1
                for (int j4 = 0; j4 < 16; ++j4) {
                    float4 t4 = *(const float4*)&tS[px * 64 + (j4 ^ sw) * 4];
                    float tv[4] = {t4.x, t4.y, t4.z, t4.w};
#pragma unroll
                    for (int jj = 0; jj < 4; ++jj) {
                        const float* hb = &hw2[(j4 * 4 + jj) * 16 + hh * 4];
                        float4 h0 = *(const float4*)hb;
                        double tv_d = (double)tv[jj];
                        hacc[0] += tv_d * (double)h0.x;
                        hacc[1] += tv_d * (double)h0.y;
                        hacc[2] += tv_d * (double)h0.z;
                        hacc[3] += tv_d * (double)h0.w;
                    }
                }
            }
            __syncthreads();   // slab reads done before next slab overwrites tS
        }
    }

    // ---- write head outputs to LDS (f64) ----
    {
        const int px = tid & 127;
        const int hh = tid >> 7;
#pragma unroll
        for (int j = 0; j < 4; ++j) houtD[px * 16 + hh * 4 + j] = hacc[j];
    }
    __syncthreads();

    // ---- decode + clip in f64, store f32 (unchanged from passing config) ----
    if (tid < 128) {
        const int px = tid;
        const int gy = ty0 + (px >> 4);
        const int gx = tx0 + (px & 15);
        if (gy < H && gx < W) {
            const int STRIDE = dStrideC[lvl];
            const int SZ     = dSizeC[lvl];
            const int LOFF   = dLoff[lvl];
#pragma unroll 1
            for (int a = 0; a < 3; ++a) {
                double score = houtD[px * 16 + a] + (double)cls_b[a];
                double rg0 = houtD[px * 16 + 3 + a * 4 + 0] + (double)box_b[a * 4 + 0];
                double rg1 = houtD[px * 16 + 3 + a * 4 + 1] + (double)box_b[a * 4 + 1];
                double rg2 = houtD[px * 16 + 3 + a * 4 + 2] + (double)box_b[a * 4 + 2];
                double rg3 = houtD[px * 16 + 3 + a * 4 + 3] + (double)box_b[a * 4 + 3];
                double ratio = (a == 0) ? 0.5 : ((a == 1) ? 1.0 : 2.0);
                double hr = sqrt(ratio), wr = 1.0 / hr;
                double wsd = wr * (double)SZ, hsd = hr * (double)SZ;
                double sx = (double)(gx * STRIDE), sy = (double)(gy * STRIDE);
                float ax0 = (float)(sx - 0.5 * wsd);
                float ay0 = (float)(sy - 0.5 * hsd);
                float ax1 = (float)(sx + 0.5 * wsd);
                float ay1 = (float)(sy + 0.5 * hsd);
                double wa = (double)ax1 - (double)ax0, ha = (double)ay1 - (double)ay0;
                double cxa = (double)ax0 + 0.5 * wa, cya = (double)ay0 + 0.5 * ha;
                double dwv = fmin(rg2, 4.135166556742356);
                double dhv = fmin(rg3, 4.135166556742356);
                double cx = rg0 * wa + cxa, cy = rg1 * ha + cya;
                double w = exp(dwv) * wa, h = exp(dhv) * ha;
                double x0 = cx - 0.5 * w, y0 = cy - 0.5 * h;
                double x1 = cx + 0.5 * w, y1 = cy + 0.5 * h;
                x0 = fmin(fmax(x0, 0.0), 1216.0);
                y0 = fmin(fmax(y0, 0.0), 800.0);
                x1 = fmin(fmax(x1, 0.0), 1216.0);
                y1 = fmin(fmax(y1, 0.0), 800.0);
                int gidx = LOFF + (gy * W + gx) * 3 + a;
                scoresA[(size_t)b * ATOTAL + gidx] = (float)score;
                float4 bx = make_float4((float)x0, (float)y0, (float)x1, (float)y1);
                *(float4*)&boxesA[((size_t)b * ATOTAL + gidx) * 4] = bx;
            }
        }
    }
}

// ---------------- per-(batch,level) top-k via 3-pass radix threshold (1024 thr) ----------------
__global__ __launch_bounds__(1024) void topk_kernel(
    const float* __restrict__ scoresA, const float* __restrict__ boxesA,
    float* __restrict__ selScore, float* __restrict__ selBox,
    int* __restrict__ selValid, int* __restrict__ selAnchor)
{
    const int lvl = blockIdx.x, b = blockIdx.y;
    const int n = dCount[lvl], loff = dLoff[lvl], seg = dSeg[lvl], k = dSegK[lvl];
    const float* sc = scoresA + (size_t)b * ATOTAL + loff;
    const int tid = threadIdx.x;

    float* oS = selScore + b * KSEL;
    float* oB = selBox + (size_t)b * KSEL * 4;
    int* oV = selValid + b * KSEL;
    int* oA = selAnchor + b * KSEL;

    auto emit = [&](int slot, int i) {
        int g = loff + i;
        float s = sc[i];
        float4 bx = *(const float4*)&boxesA[((size_t)b * ATOTAL + g) * 4];
        oS[seg + slot] = s;
        *(float4*)&oB[(size_t)(seg + slot) * 4] = bx;
        oV[seg + slot] = ((bx.z - bx.x) >= 1e-3f && (bx.w - bx.y) >= 1e-3f) ? 1 : 0;
        oA[seg + slot] = g;
    };

    if (n <= k) {
        for (int i = tid; i < n; i += 1024) emit(i, i);
        return;
    }

    __shared__ uint hist[2048];
    __shared__ uint suf[2][1024];
    __shared__ uint sh_bin, sh_krem;
    __shared__ uint cntG, cntE;
    __shared__ int stash[64];

    uint krem = (uint)k;
    uint prefix = 0;
    for (int pass = 0; pass < 3; ++pass) {
        for (int e = tid; e < 2048; e += 1024) hist[e] = 0;
        __syncthreads();
        for (int i = tid; i < n; i += 1024) {
            uint key = fkey(sc[i]);
            uint bin; bool sel;
            if (pass == 0)      { sel = true;                      bin = key >> 21; }
            else if (pass == 1) { sel = ((key >> 21) == prefix);   bin = (key >> 10) & 0x7FFu; }
            else                { sel = ((key >> 10) == prefix);   bin = key & 0x3FFu; }
            if (sel) atomicAdd(&hist[bin], 1u);
        }
        __syncthreads();
        // ---- parallel bin selection: pair-sum + inclusive suffix scan (10 steps) ----
        {
            const int nb = (pass == 2) ? 1024 : 2048;
            uint pv = 0;
            if (2 * tid < nb)     pv += hist[2 * tid];
            if (2 * tid + 1 < nb) pv += hist[2 * tid + 1];
            suf[0][tid] = pv;
            __syncthreads();
            int src = 0;
#pragma unroll
            for (int off2 = 1; off2 < 1024; off2 <<= 1) {
                uint v = suf[src][tid] + ((tid + off2 < 1024) ? suf[src][tid + off2] : 0u);
                suf[src ^ 1][tid] = v;
                __syncthreads();
                src ^= 1;
            }
            uint SUFt1 = (tid + 1 < 1024) ? suf[src][tid + 1] : 0u;
            uint h1 = (2 * tid + 1 < nb) ? hist[2 * tid + 1] : 0u;
            if (2 * tid + 1 < nb && SUFt1 < krem && SUFt1 + h1 >= krem) {
                sh_bin = (uint)(2 * tid + 1); sh_krem = krem - SUFt1;
            }
            uint S0 = SUFt1 + h1;
            if (2 * tid < nb) {
                uint h0 = hist[2 * tid];
                if (S0 < krem && S0 + h0 >= krem) {
                    sh_bin = (uint)(2 * tid); sh_krem = krem - S0;
                }
            }
        }
        __syncthreads();
        uint bin = sh_bin; krem = sh_krem;
        if (pass == 0)      prefix = bin;
        else if (pass == 1) prefix = (prefix << 11) | bin;
        else                prefix = (prefix << 10) | bin;
        __syncthreads();
    }
    const uint T = prefix;
    const uint need_eq = krem;
    if (tid == 0) { cntG = 0; cntE = 0; }
    __syncthreads();
    for (int i = tid; i < n; i += 1024) {
        uint key = fkey(sc[i]);
        if (key > T) {
            uint pos = atomicAdd(&cntG, 1u);
            emit((int)pos, i);
        } else if (key == T) {
            uint e = atomicAdd(&cntE, 1u);
            if (e < 64) stash[e] = i;
        }
    }
    __syncthreads();
    if (tid == 0) {
        uint ne = cntE < 64u ? cntE : 64u;
        uint base = cntG;   // == k - need_eq
        for (uint t2 = 0; t2 < need_eq; ++t2) {
            int best = -1, bj = -1;
            for (uint j2 = 0; j2 < ne; ++j2) {
                int v = stash[j2];
                if (v >= 0 && (best < 0 || v < best)) { best = v; bj = j2; }
            }
            if (bj >= 0) { stash[bj] = -1; emit((int)(base + t2), best); }
            else emit((int)(base + t2), 0);
        }
    }
}

// ---------------- per-batch descending sort (score, then anchor-idx asc) ----------------
__global__ __launch_bounds__(1024) void sort_kernel(
    const float* __restrict__ selScore, const float* __restrict__ selBox,
    const int* __restrict__ selValid, const int* __restrict__ selAnchor,
    int* __restrict__ sortedSlot, float* __restrict__ sortedBoxOff,
    ull* __restrict__ validMask)
{
    const int b = blockIdx.x, tid = threadIdx.x;
    __shared__ ull  skey[8192];
    __shared__ uint spay[8192];
    __shared__ ull  svm[NW];

    for (int i = tid; i < 8192; i += 1024) {
        ull kk2; uint pp;
        if (i < KSEL) {
            float s = selScore[b * KSEL + i];
            int v = selValid[b * KSEL + i];
            uint k32 = v ? fkey(s) : 0x007FFFFFu;
            uint a32 = 0xFFFFFFFFu - (uint)selAnchor[b * KSEL + i];
            kk2 = ((ull)k32 << 32) | a32; pp = (uint)i;
        } else { kk2 = 0ull; pp = 0xFFFFFFFFu; }
        skey[i] = kk2; spay[i] = pp;
    }
    __syncthreads();
    for (uint kk = 2; kk <= 8192; kk <<= 1) {
        for (uint j = kk >> 1; j > 0; j >>= 1) {
            for (int i = tid; i < 8192; i += 1024) {
                uint ixj = (uint)i ^ j;
                if (ixj > (uint)i) {
                    bool up = ((((uint)i) & kk) == 0);
                    ull a = skey[i], c = skey[ixj];
                    bool sw = up ? (a < c) : (a > c);
                    if (sw) {
                        skey[i] = c; skey[ixj] = a;
                        uint tp = spay[i]; spay[i] = spay[ixj]; spay[ixj] = tp;
                    }
                }
            }
            __syncthreads();
        }
    }
    for (int i = tid; i < NW; i += 1024) svm[i] = 0ull;
    __syncthreads();
    for (int i = tid; i < KSEL; i += 1024) {
        uint slot = spay[i];
        sortedSlot[b * KSEL + i] = (int)slot;
        int v = selValid[b * KSEL + slot];
        if (v) atomicOr(&svm[i >> 6], 1ull << (i & 63));
        int lvl = (int)slot / 1000;
        float off = 1217.0f * (float)lvl;
        float4 bx = *(const float4*)&selBox[((size_t)b * KSEL + slot) * 4];
        bx.x += off; bx.y += off; bx.z += off; bx.w += off;
        *(float4*)&sortedBoxOff[((size_t)b * KSEL + i) * 4] = bx;
    }
    __syncthreads();
    for (int i = tid; i < NW; i += 1024) validMask[b * NW + i] = svm[i];
}

// ---------------- NMS pairwise suppression bitmask (upper-triangle launch) ----------------
__global__ __launch_bounds__(64) void nms_mask(const float* __restrict__ sortedBoxOff,
                                               ull* __restrict__ mat)
{
    const int b = blockIdx.y;
    const int tid = threadIdx.x;
    int rem = blockIdx.x, ib = 0;
    while (rem >= NW - ib) { rem -= NW - ib; ++ib; }
    const int jb = ib + rem;

    __shared__ float4 bj[64];
    __shared__ float  aj[64];
    const int j0 = jb * 64;
    const int jn = (KSEL - j0) < 64 ? (KSEL - j0) : 64;
    if (tid < jn) {
        float4 v = *(const float4*)&sortedBoxOff[((size_t)b * KSEL + j0 + tid) * 4];
        bj[tid] = v; aj[tid] = (v.z - v.x) * (v.w - v.y);
    }
    __syncthreads();
    const int i = ib * 64 + tid;
    if (i >= KSEL) return;
    float4 bi = *(const float4*)&sortedBoxOff[((size_t)b * KSEL + i) * 4];
    float ai = (bi.z - bi.x) * (bi.w - bi.y);
    ull m = 0ull;
    for (int jj = 0; jj < jn; ++jj) {
        int j = j0 + jj;
        if (j <= i) continue;
        float4 bb = bj[jj];
        float ltx = fmaxf(bi.x, bb.x), lty = fmaxf(bi.y, bb.y);
        float rbx = fminf(bi.z, bb.z), rby = fminf(bi.w, bb.w);
        float wx = fmaxf(rbx - ltx, 0.f), wy = fmaxf(rby - lty, 0.f);
        float inter = wx * wy;
        float iou = inter / (ai + aj[jj] - inter + 1e-9f);
        if (iou > 0.7f) m |= (1ull << jj);
    }
    mat[((size_t)b * KSEL + i) * NW + jb] = m;
}

// ---------------- greedy scan (1 wave/batch, double-buffered 16-row prefetch) ----------------
#define LOADG(RA, RB, G) { int base0 = (G) * 16; \
    _Pragma("unroll") for (int d = 0; d < 16; ++d) { int i = base0 + d; \
        RA[d] = (i < KSEL) ? mb[(size_t)i * NW + lane] : 0ull; \
        RB[d] = (hasHi && i < KSEL) ? mb[(size_t)i * NW + 64 + lane] : 0ull; } }
#define PROCG(RA, RB, G) { int base0 = (G) * 16; \
    _Pragma("unroll") for (int d = 0; d < 16; ++d) { int i = base0 + d; \
        if (i < KSEL) { int wi = i >> 6; \
            ull act0 = v0 & ~s0, act1 = v1 & ~s1; \
            ull aw = (wi < 64) ? __shfl(act0, wi, 64) : __shfl(act1, wi - 64, 64); \
            if ((aw >> (i & 63)) & 1ull) { \
                s0 |= (lane >= wi) ? RA[d] : 0ull; \
                s1 |= (lane + 64 >= wi) ? RB[d] : 0ull; \
                if (lane == 0) keptPos[b * POST_NMS + nk] = i; \
                ++nk; \
                if (nk == POST_NMS) { if (lane == 0) nkOut[b] = nk; return; } } } } }

__global__ __launch_bounds__(64) void nms_scan(const ull* __restrict__ mat,
                                               const ull* __restrict__ validMask,
                                               int* __restrict__ keptPos,
                                               int* __restrict__ nkOut)
{
    const int b = blockIdx.x, lane = threadIdx.x;
    const bool hasHi = lane < NW - 64;
    ull v0 = validMask[b * NW + lane];
    ull v1 = hasHi ? validMask[b * NW + 64 + lane] : 0ull;
    ull s0 = 0ull, s1 = 0ull;
    int nk = 0;
    const ull* mb = mat + (size_t)b * KSEL * NW;
    const int NG = (KSEL + 15) / 16;   // 297

    ull A0[16], B0[16], A1[16], B1[16];
    LOADG(A0, B0, 0);
    for (int g = 0; g < NG; g += 2) {
        if (g + 1 < NG) LOADG(A1, B1, g + 1);
        PROCG(A0, B0, g);
        if (g + 2 < NG) LOADG(A0, B0, g + 2);
        if (g + 1 < NG) PROCG(A1, B1, g + 1);
    }
    if (lane == 0) nkOut[b] = nk;
}

// ---------------- final output ----------------
__global__ __launch_bounds__(256) void out_kernel(
    const int* __restrict__ keptPos, const int* __restrict__ nkOut,
    const int* __restrict__ sortedSlot,
    const float* __restrict__ selBox, const float* __restrict__ selScore,
    float* __restrict__ out)
{
    int t = blockIdx.x * 256 + threadIdx.x;
    if (t >= BATCH * POST_NMS) return;
    int b = t / POST_NMS, row = t - b * POST_NMS;
    float4 bx = make_float4(0.f, 0.f, 0.f, 0.f);
    float sc = -1e9f;
    if (row < nkOut[b]) {
        int i = keptPos[b * POST_NMS + row];
        int slot = sortedSlot[b * KSEL + i];
        bx = *(const float4*)&selBox[((size_t)b * KSEL + slot) * 4];
        sc = selScore[b * KSEL + slot];
    }
    *(float4*)&out[(size_t)t * 4] = bx;
    out[BATCH * POST_NMS * 4 + t] = sc;
}

// ---------------- host launch ----------------
extern "C" void kernel_launch(void* const* d_in, const int* in_sizes, int n_in,
                              void* d_out, int out_size, void* d_ws, size_t ws_size,
                              hipStream_t stream)
{
    (void)in_sizes; (void)n_in; (void)out_size; (void)ws_size;
    const float* feat[5] = {(const float*)d_in[0], (const float*)d_in[1],
                            (const float*)d_in[2], (const float*)d_in[3],
                            (const float*)d_in[4]};
    const float* conv_w = (const float*)d_in[5];
    const float* conv_b = (const float*)d_in[6];
    const float* cls_w  = (const float*)d_in[7];
    const float* cls_b  = (const float*)d_in[8];
    const float* box_w  = (const float*)d_in[9];
    const float* box_b  = (const float*)d_in[10];
    float* out = (float*)d_out;

    char* ws = (char*)d_ws;
    size_t off = 0;
    auto carve = [&](size_t bytes) -> void* {
        void* p = (void*)(ws + off);
        off += (bytes + 255) & ~(size_t)255;
        return p;
    };
    ushort* wB         = (ushort*)carve((size_t)WB_ELEMS * 2);
    float* scoresA     = (float*)carve((size_t)BATCH * ATOTAL * 4);
    float* boxesA      = (float*)carve((size_t)BATCH * ATOTAL * 16);
    float* selScore    = (float*)carve((size_t)BATCH * KSEL * 4);
    float* selBox      = (float*)carve((size_t)BATCH * KSEL * 16);
    int*   selValid    = (int*)  carve((size_t)BATCH * KSEL * 4);
    int*   selAnchor   = (int*)  carve((size_t)BATCH * KSEL * 4);
    int*   sortedSlot  = (int*)  carve((size_t)BATCH * KSEL * 4);
    float* sortedBoxOff= (float*)carve((size_t)BATCH * KSEL * 16);
    ull*   validMask   = (ull*)  carve((size_t)BATCH * NW * 8);
    ull*   mat         = (ull*)  carve((size_t)BATCH * KSEL * NW * 8);
    int*   keptPos     = (int*)  carve((size_t)BATCH * POST_NMS * 4);
    int*   nkOut       = (int*)  carve(64);

    wt_kernel<<<(WB_ELEMS + 255) / 256, 256, 0, stream>>>(conv_w, wB);

    conv_mfma_all<<<dim3(656, BATCH), 512, 0, stream>>>(
        feat[0], feat[1], feat[2], feat[3], feat[4], wB, conv_b,
        cls_w, cls_b, box_w, box_b, scoresA, boxesA);

    topk_kernel<<<dim3(5, BATCH), 1024, 0, stream>>>(scoresA, boxesA, selScore, selBox, selValid, selAnchor);
    sort_kernel<<<dim3(BATCH), 1024, 0, stream>>>(selScore, selBox, selValid, selAnchor, sortedSlot, sortedBoxOff, validMask);
    nms_mask<<<dim3(NPAIRS, BATCH), 64, 0, stream>>>(sortedBoxOff, mat);
    nms_scan<<<dim3(BATCH), 64, 0, stream>>>(mat, validMask, keptPos, nkOut);
    out_kernel<<<dim3((BATCH * POST_NMS + 255) / 256), 256, 0, stream>>>(keptPos, nkOut, sortedSlot, selBox, selScore, out);
}

// Round 15
// 1425.010 us; speedup vs baseline: 1.1244x; 1.1244x over previous
//
#include <hip/hip_runtime.h>
#include <hip/hip_fp16.h>
#include <stdint.h>
#include <math.h>

typedef unsigned int uint;
typedef unsigned short ushort;
typedef unsigned long long ull;
typedef __attribute__((ext_vector_type(8))) _Float16 f16x8;
typedef __attribute__((ext_vector_type(4))) float f32x4;

#define BATCH 2
#define ATOTAL 242991
#define KSEL 4741
#define NW 75
#define POST_NMS 1000
#define WB_ELEMS (2*8*3*3*2*8*64*8)   // 1,179,648 u16 = 2.25 MB
#define NPAIRS 2850                   // 75*76/2 upper-triangle block pairs

// runtime-indexed device copies
__device__ __constant__ int dLoff[5]  = {0,182400,228000,239400,242250};
__device__ __constant__ int dCount[5] = {182400,45600,11400,2850,741};
__device__ __constant__ int dSeg[5]   = {0,1000,2000,3000,4000};
__device__ __constant__ int dSegK[5]  = {1000,1000,1000,1000,741};
__device__ __constant__ int dHc[5]     = {200,100,50,25,13};
__device__ __constant__ int dWc[5]     = {304,152,76,38,19};
__device__ __constant__ int dTilesX[5] = {19,10,5,3,2};
__device__ __constant__ int dCumT[6]   = {0,475,605,640,652,656};   // 8x16 tiles
__device__ __constant__ int dStrideC[5]= {4,8,16,32,64};
__device__ __constant__ int dSizeC[5]  = {32,64,128,256,512};

__device__ __forceinline__ uint fkey(float f) {
    uint u = __float_as_uint(f);
    return (u & 0x80000000u) ? ~u : (u | 0x80000000u);
}
__device__ __forceinline__ ushort h2u(__half h) {
    union { __half h; ushort u; } x; x.h = h; return x.u;
}

// ---------------- weight gen: conv_w -> wB fp16 (h, m*1024), slab-contiguous per (ocg,icblk,dy) ----
// layout: [ocg2][icblk8][dy3][dx3][pl2][nt8][lane64][e8] u16  (one (ocg,icblk,dy) slab = 24576 u16)
__global__ __launch_bounds__(256) void wt_kernel(const float* __restrict__ conv_w,
                                                 ushort* __restrict__ wB) {
    int t = blockIdx.x * 256 + threadIdx.x;
    if (t >= WB_ELEMS) return;
    int e    = t & 7;
    int lane = (t >> 3) & 63;
    int nt   = (t >> 9) & 7;
    int pl   = (t >> 12) & 1;
    int r    = t >> 13;            // dx + 3*(dy + 3*(icblk + 8*ocg))
    int dx = r % 3; r /= 3;
    int dy = r % 3; r /= 3;
    int icblk = r & 7;
    int ocg = r >> 3;
    int oc = ocg * 128 + nt * 16 + (lane & 15);
    int ic = icblk * 32 + ((lane >> 4) << 3) + e;
    float v = conv_w[(size_t)oc * 2304 + ic * 9 + dy * 3 + dx];
    __half h = __float2half(v);
    float rr = (v - __half2float(h)) * 1024.0f;   // scaled residual stays fp16-normal
    __half m = __float2half(rr);
    wB[t] = (pl == 0) ? h2u(h) : h2u(m);
}

// ---------------- MFMA conv3x3 (fp16x2 scaled-m split) + f64 heads/decode ----
// Round-15: EXACT r11 conv config (measured best, 863us): 8x16 tile, 512 thr (8 waves,
// each 2mi x 4ni), single-buffered 48KB B slab + reg-prefetch, 2 barriers/step,
// no setprio (r12: -6%), no dbuf (r14: -19%), no 16x16 tile (r13: spill).
// Math order (icblk,dy,dx ascending per accumulator) bit-identical.
__global__ __launch_bounds__(512) void conv_mfma_all(
    const float* __restrict__ f0, const float* __restrict__ f1,
    const float* __restrict__ f2, const float* __restrict__ f3,
    const float* __restrict__ f4, const ushort* __restrict__ wB,
    const float* __restrict__ conv_b,
    const float* __restrict__ cls_w, const float* __restrict__ cls_b,
    const float* __restrict__ box_w, const float* __restrict__ box_b,
    float* __restrict__ scoresA, float* __restrict__ boxesA)
{
    const int bidx = blockIdx.x;
    const int b    = blockIdx.y;
    const int tid  = threadIdx.x;

    int lvl = 0;
#pragma unroll
    for (int l = 1; l < 5; ++l) if (bidx >= dCumT[l]) lvl = l;
    const int tile   = bidx - dCumT[lvl];
    const int H      = dHc[lvl], W = dWc[lvl];
    const int TILESX = dTilesX[lvl];
    const int ty0    = (tile / TILESX) * 8;
    const int tx0    = (tile % TILESX) * 16;
    const int HW     = H * W;
    const float* feat = (lvl == 0) ? f0 : (lvl == 1) ? f1 : (lvl == 2) ? f2 : (lvl == 3) ? f3 : f4;
    const float* fb = feat + (size_t)b * 256 * HW;

    __shared__ __align__(16) char uni[72192];
    ushort* halo = (ushort*)uni;                 // [2pl][5760] u16 = 23040 B
    ushort* ldsB = (ushort*)(uni + 23040);       // [3dx][2pl][8nt][64lane][8e] = 49152 B
    float*  tS   = (float*)uni;                  // 32768 B (aliases halo+B head, conv done)
    float*  hw2  = (float*)(uni + 32768);        // 4096 B (inside B region, conv done)
    double* houtD= (double*)uni;                 // 16384 B (aliases tS, slabs done)

    const int lane = tid & 63, wave = tid >> 6;
    const int wm = wave >> 1, wn = wave & 1;
    const int g = lane >> 4, col = lane & 15;
    const int laneA = g * 1440 + col * 8;        // u16 idx, lane-constant part

    // halo staging coords (icblk-invariant): 5760 elems / 512 threads = 12 slots
    int  hdst[12]; int hoff[12]; bool hval[12];
#pragma unroll
    for (int j = 0; j < 12; ++j) {
        int e = tid + j * 512;
        hdst[j] = -1; hoff[j] = 0; hval[j] = false;
        if (e < 5760) {
            int ic = e / 180, rem = e - ic * 180;
            int hrow = rem / 18, hcol = rem - hrow * 18;
            int gy = ty0 + hrow - 1, gx = tx0 + hcol - 1;
            hdst[j] = (((ic >> 3) * 10 + hrow) * 18 + hcol) * 8 + (ic & 7);
            if (gy >= 0 && gy < H && gx >= 0 && gx < W) {
                hval[j] = true; hoff[j] = ic * HW + gy * W + gx;
            }
        }
    }

    double hacc[4] = {0,0,0,0};   // per-thread f64 head accumulators (4 heads)

    // B prefetch registers (6 x uint4 per thread = 48 KB slab at 512 threads)
    uint4 Br0, Br1, Br2, Br3, Br4, Br5;
    {
        const uint4* gq = (const uint4*)wB;
        Br0 = gq[tid];        Br1 = gq[tid + 512];
        Br2 = gq[tid + 1024]; Br3 = gq[tid + 1536];
        Br4 = gq[tid + 2048]; Br5 = gq[tid + 2560];
    }

#pragma unroll 1
    for (int ocg = 0; ocg < 2; ++ocg) {
        f32x4 accH[2][4], accM[2][4];
#pragma unroll
        for (int mi = 0; mi < 2; ++mi)
#pragma unroll
            for (int ni = 0; ni < 4; ++ni) {
                accH[mi][ni] = (f32x4){0.f, 0.f, 0.f, 0.f};
                accM[mi][ni] = (f32x4){0.f, 0.f, 0.f, 0.f};
            }

#pragma unroll 1
        for (int s = 0; s < 24; ++s) {        // step = (icblk, dy)
            const int icblk = s / 3;
            const int dy    = s - icblk * 3;

            __syncthreads();   // prior step's halo/ldsB reads (and epilogue reads) done
            // ---- stage halo at icblk start: batch-issue 12 loads, then convert+write ----
            if (dy == 0) {
                float hv[12];
                const float* fcb = fb + (size_t)icblk * 32 * HW;
#pragma unroll
                for (int j = 0; j < 12; ++j)
                    hv[j] = hval[j] ? fcb[hoff[j]] : 0.f;
#pragma unroll
                for (int j = 0; j < 12; ++j) {
                    if (hdst[j] >= 0) {
                        float v = hv[j];
                        __half h = __float2half(v);
                        float rr = (v - __half2float(h)) * 1024.0f;
                        __half m = __float2half(rr);
                        int li = hdst[j];
                        halo[li] = h2u(h); halo[5760 + li] = h2u(m);
                    }
                }
            }
            // ---- write prefetched B slab (48 KB) to LDS ----
            {
                uint4* lq = (uint4*)ldsB;
                lq[tid] = Br0;         lq[tid + 512]  = Br1;
                lq[tid + 1024] = Br2;  lq[tid + 1536] = Br3;
                lq[tid + 2048] = Br4;  lq[tid + 2560] = Br5;
            }
            __syncthreads();   // halo + B visible
            // ---- issue next slab's loads (hidden under MFMA phase) ----
            {
                int gstep = ocg * 24 + s + 1;
                if (gstep < 48) {
                    const uint4* gq = (const uint4*)(wB + (size_t)gstep * 24576);
                    Br0 = gq[tid];        Br1 = gq[tid + 512];
                    Br2 = gq[tid + 1024]; Br3 = gq[tid + 1536];
                    Br4 = gq[tid + 2048]; Br5 = gq[tid + 2560];
                }
            }
            // ---- compute: 3 dx sub-steps, 72 MFMAs per wave ----
#pragma unroll 1
            for (int dx = 0; dx < 3; ++dx) {
                f16x8 Ah[2], Am[2];
                const int abase = laneA + dx * 8 + (2 * wm + dy) * 144;
#pragma unroll
                for (int mi = 0; mi < 2; ++mi) {
                    Ah[mi] = *(const f16x8*)(halo + abase + mi * 144);
                    Am[mi] = *(const f16x8*)(halo + 5760 + abase + mi * 144);
                }
#pragma unroll
                for (int ni = 0; ni < 4; ++ni) {
                    const int nt = 4 * wn + ni;
                    f16x8 Bh = *(const f16x8*)(ldsB + (size_t)(dx * 16 + nt) * 512 + lane * 8);
                    f16x8 Bm = *(const f16x8*)(ldsB + (size_t)(dx * 16 + 8 + nt) * 512 + lane * 8);
#pragma unroll
                    for (int mi = 0; mi < 2; ++mi) {
                        f32x4 cH = accH[mi][ni];
                        f32x4 cM = accM[mi][ni];
                        cH = __builtin_amdgcn_mfma_f32_16x16x32_f16(Ah[mi], Bh, cH, 0, 0, 0);
                        cM = __builtin_amdgcn_mfma_f32_16x16x32_f16(Ah[mi], Bm, cM, 0, 0, 0);
                        cM = __builtin_amdgcn_mfma_f32_16x16x32_f16(Am[mi], Bh, cM, 0, 0, 0);
                        accH[mi][ni] = cH;
                        accM[mi][ni] = cM;
                    }
                }
            }
        }
        __syncthreads();   // all halo/ldsB reads done -> tS may overwrite
        // ---- writeout + f64 head contraction, 2 slabs of 64 oc (oc ascending) ----
        float cb[4];
#pragma unroll
        for (int ni = 0; ni < 4; ++ni)
            cb[ni] = conv_b[ocg * 128 + (4 * wn + ni) * 16 + col];

#pragma unroll 1
        for (int s2 = 0; s2 < 2; ++s2) {
            if (wn == s2) {
#pragma unroll
                for (int mi = 0; mi < 2; ++mi) {
#pragma unroll
                    for (int r = 0; r < 4; ++r) {
                        int px = (2 * wm + mi) * 16 + 4 * g + r;
                        int sw = px & 15;
#pragma unroll
                        for (int ni = 0; ni < 4; ++ni) {
                            int slot = (ni * 4 + (col >> 2)) ^ sw;
                            float val = accH[mi][ni][r] + accM[mi][ni][r] * 0.0009765625f;
                            tS[px * 64 + slot * 4 + (col & 3)] =
                                fmaxf(val + cb[ni], 0.f);
                        }
                    }
                }
            }
            // stage head weights for this 64-oc slab (threads 0..255)
            if (tid < 256) {
                const int oc2 = tid >> 2;
                const int h0  = (tid & 3) * 4;
                const int oc  = ocg * 128 + s2 * 64 + oc2;
                float vv[4];
#pragma unroll
                for (int q = 0; q < 4; ++q) {
                    int h = h0 + q;
                    vv[q] = (h < 3) ? cls_w[h * 256 + oc]
                          : (h < 15) ? box_w[(h - 3) * 256 + oc] : 0.f;
                }
                *(float4*)&hw2[oc2 * 16 + h0] = make_float4(vv[0], vv[1], vv[2], vv[3]);
            }
            __syncthreads();
            // accumulate: px = tid&127, head-quarter = tid>>7 (oc ascending within slab)
            {
                const int px = tid & 127;
                const int hh = tid >> 7;           // 0..3, heads hh*4..hh*4+3
                const int sw = px & 15;
#pragma unroll 1
                for (int j4 = 0; j4 < 16; ++j4) {
                    float4 t4 = *(const float4*)&tS[px * 64 + (j4 ^ sw) * 4];
                    float tv[4] = {t4.x, t4.y, t4.z, t4.w};
#pragma unroll
                    for (int jj = 0; jj < 4; ++jj) {
                        const float* hb = &hw2[(j4 * 4 + jj) * 16 + hh * 4];
                        float4 h0 = *(const float4*)hb;
                        double tv_d = (double)tv[jj];
                        hacc[0] += tv_d * (double)h0.x;
                        hacc[1] += tv_d * (double)h0.y;
                        hacc[2] += tv_d * (double)h0.z;
                        hacc[3] += tv_d * (double)h0.w;
                    }
                }
            }
            __syncthreads();   // slab reads done before next slab overwrites tS
        }
    }

    // ---- write head outputs to LDS (f64) ----
    {
        const int px = tid & 127;
        const int hh = tid >> 7;
#pragma unroll
        for (int j = 0; j < 4; ++j) houtD[px * 16 + hh * 4 + j] = hacc[j];
    }
    __syncthreads();

    // ---- decode + clip in f64, store f32 (unchanged from passing config) ----
    if (tid < 128) {
        const int px = tid;
        const int gy = ty0 + (px >> 4);
        const int gx = tx0 + (px & 15);
        if (gy < H && gx < W) {
            const int STRIDE = dStrideC[lvl];
            const int SZ     = dSizeC[lvl];
            const int LOFF   = dLoff[lvl];
#pragma unroll 1
            for (int a = 0; a < 3; ++a) {
                double score = houtD[px * 16 + a] + (double)cls_b[a];
                double rg0 = houtD[px * 16 + 3 + a * 4 + 0] + (double)box_b[a * 4 + 0];
                double rg1 = houtD[px * 16 + 3 + a * 4 + 1] + (double)box_b[a * 4 + 1];
                double rg2 = houtD[px * 16 + 3 + a * 4 + 2] + (double)box_b[a * 4 + 2];
                double rg3 = houtD[px * 16 + 3 + a * 4 + 3] + (double)box_b[a * 4 + 3];
                double ratio = (a == 0) ? 0.5 : ((a == 1) ? 1.0 : 2.0);
                double hr = sqrt(ratio), wr = 1.0 / hr;
                double wsd = wr * (double)SZ, hsd = hr * (double)SZ;
                double sx = (double)(gx * STRIDE), sy = (double)(gy * STRIDE);
                float ax0 = (float)(sx - 0.5 * wsd);
                float ay0 = (float)(sy - 0.5 * hsd);
                float ax1 = (float)(sx + 0.5 * wsd);
                float ay1 = (float)(sy + 0.5 * hsd);
                double wa = (double)ax1 - (double)ax0, ha = (double)ay1 - (double)ay0;
                double cxa = (double)ax0 + 0.5 * wa, cya = (double)ay0 + 0.5 * ha;
                double dwv = fmin(rg2, 4.135166556742356);
                double dhv = fmin(rg3, 4.135166556742356);
                double cx = rg0 * wa + cxa, cy = rg1 * ha + cya;
                double w = exp(dwv) * wa, h = exp(dhv) * ha;
                double x0 = cx - 0.5 * w, y0 = cy - 0.5 * h;
                double x1 = cx + 0.5 * w, y1 = cy + 0.5 * h;
                x0 = fmin(fmax(x0, 0.0), 1216.0);
                y0 = fmin(fmax(y0, 0.0), 800.0);
                x1 = fmin(fmax(x1, 0.0), 1216.0);
                y1 = fmin(fmax(y1, 0.0), 800.0);
                int gidx = LOFF + (gy * W + gx) * 3 + a;
                scoresA[(size_t)b * ATOTAL + gidx] = (float)score;
                float4 bx = make_float4((float)x0, (float)y0, (float)x1, (float)y1);
                *(float4*)&boxesA[((size_t)b * ATOTAL + gidx) * 4] = bx;
            }
        }
    }
}

// ---------------- per-(batch,level) top-k via 3-pass radix threshold (1024 thr) ----------------
// parallel pair-sum + 10-step suffix scan for bin selection (r12: tail 664->563us)
__global__ __launch_bounds__(1024) void topk_kernel(
    const float* __restrict__ scoresA, const float* __restrict__ boxesA,
    float* __restrict__ selScore, float* __restrict__ selBox,
    int* __restrict__ selValid, int* __restrict__ selAnchor)
{
    const int lvl = blockIdx.x, b = blockIdx.y;
    const int n = dCount[lvl], loff = dLoff[lvl], seg = dSeg[lvl], k = dSegK[lvl];
    const float* sc = scoresA + (size_t)b * ATOTAL + loff;
    const int tid = threadIdx.x;

    float* oS = selScore + b * KSEL;
    float* oB = selBox + (size_t)b * KSEL * 4;
    int* oV = selValid + b * KSEL;
    int* oA = selAnchor + b * KSEL;

    auto emit = [&](int slot, int i) {
        int g = loff + i;
        float s = sc[i];
        float4 bx = *(const float4*)&boxesA[((size_t)b * ATOTAL + g) * 4];
        oS[seg + slot] = s;
        *(float4*)&oB[(size_t)(seg + slot) * 4] = bx;
        oV[seg + slot] = ((bx.z - bx.x) >= 1e-3f && (bx.w - bx.y) >= 1e-3f) ? 1 : 0;
        oA[seg + slot] = g;
    };

    if (n <= k) {
        for (int i = tid; i < n; i += 1024) emit(i, i);
        return;
    }

    __shared__ uint hist[2048];
    __shared__ uint suf[2][1024];
    __shared__ uint sh_bin, sh_krem;
    __shared__ uint cntG, cntE;
    __shared__ int stash[64];

    uint krem = (uint)k;
    uint prefix = 0;
    for (int pass = 0; pass < 3; ++pass) {
        for (int e = tid; e < 2048; e += 1024) hist[e] = 0;
        __syncthreads();
        for (int i = tid; i < n; i += 1024) {
            uint key = fkey(sc[i]);
            uint bin; bool sel;
            if (pass == 0)      { sel = true;                      bin = key >> 21; }
            else if (pass == 1) { sel = ((key >> 21) == prefix);   bin = (key >> 10) & 0x7FFu; }
            else                { sel = ((key >> 10) == prefix);   bin = key & 0x3FFu; }
            if (sel) atomicAdd(&hist[bin], 1u);
        }
        __syncthreads();
        // ---- parallel bin selection: pair-sum + inclusive suffix scan (10 steps) ----
        {
            const int nb = (pass == 2) ? 1024 : 2048;
            uint pv = 0;
            if (2 * tid < nb)     pv += hist[2 * tid];
            if (2 * tid + 1 < nb) pv += hist[2 * tid + 1];
            suf[0][tid] = pv;
            __syncthreads();
            int src = 0;
#pragma unroll
            for (int off2 = 1; off2 < 1024; off2 <<= 1) {
                uint v = suf[src][tid] + ((tid + off2 < 1024) ? suf[src][tid + off2] : 0u);
                suf[src ^ 1][tid] = v;
                __syncthreads();
                src ^= 1;
            }
            uint SUFt1 = (tid + 1 < 1024) ? suf[src][tid + 1] : 0u;
            uint h1 = (2 * tid + 1 < nb) ? hist[2 * tid + 1] : 0u;
            if (2 * tid + 1 < nb && SUFt1 < krem && SUFt1 + h1 >= krem) {
                sh_bin = (uint)(2 * tid + 1); sh_krem = krem - SUFt1;
            }
            uint S0 = SUFt1 + h1;
            if (2 * tid < nb) {
                uint h0 = hist[2 * tid];
                if (S0 < krem && S0 + h0 >= krem) {
                    sh_bin = (uint)(2 * tid); sh_krem = krem - S0;
                }
            }
        }
        __syncthreads();
        uint bin = sh_bin; krem = sh_krem;
        if (pass == 0)      prefix = bin;
        else if (pass == 1) prefix = (prefix << 11) | bin;
        else                prefix = (prefix << 10) | bin;
        __syncthreads();
    }
    const uint T = prefix;
    const uint need_eq = krem;
    if (tid == 0) { cntG = 0; cntE = 0; }
    __syncthreads();
    for (int i = tid; i < n; i += 1024) {
        uint key = fkey(sc[i]);
        if (key > T) {
            uint pos = atomicAdd(&cntG, 1u);
            emit((int)pos, i);
        } else if (key == T) {
            uint e = atomicAdd(&cntE, 1u);
            if (e < 64) stash[e] = i;
        }
    }
    __syncthreads();
    if (tid == 0) {
        uint ne = cntE < 64u ? cntE : 64u;
        uint base = cntG;   // == k - need_eq
        for (uint t2 = 0; t2 < need_eq; ++t2) {
            int best = -1, bj = -1;
            for (uint j2 = 0; j2 < ne; ++j2) {
                int v = stash[j2];
                if (v >= 0 && (best < 0 || v < best)) { best = v; bj = j2; }
            }
            if (bj >= 0) { stash[bj] = -1; emit((int)(base + t2), best); }
            else emit((int)(base + t2), 0);
        }
    }
}

// ---------------- per-batch descending sort (score, then anchor-idx asc) ----------------
__global__ __launch_bounds__(1024) void sort_kernel(
    const float* __restrict__ selScore, const float* __restrict__ selBox,
    const int* __restrict__ selValid, const int* __restrict__ selAnchor,
    int* __restrict__ sortedSlot, float* __restrict__ sortedBoxOff,
    ull* __restrict__ validMask)
{
    const int b = blockIdx.x, tid = threadIdx.x;
    __shared__ ull  skey[8192];
    __shared__ uint spay[8192];
    __shared__ ull  svm[NW];

    for (int i = tid; i < 8192; i += 1024) {
        ull kk2; uint pp;
        if (i < KSEL) {
            float s = selScore[b * KSEL + i];
            int v = selValid[b * KSEL + i];
            uint k32 = v ? fkey(s) : 0x007FFFFFu;
            uint a32 = 0xFFFFFFFFu - (uint)selAnchor[b * KSEL + i];
            kk2 = ((ull)k32 << 32) | a32; pp = (uint)i;
        } else { kk2 = 0ull; pp = 0xFFFFFFFFu; }
        skey[i] = kk2; spay[i] = pp;
    }
    __syncthreads();
    for (uint kk = 2; kk <= 8192; kk <<= 1) {
        for (uint j = kk >> 1; j > 0; j >>= 1) {
            for (int i = tid; i < 8192; i += 1024) {
                uint ixj = (uint)i ^ j;
                if (ixj > (uint)i) {
                    bool up = ((((uint)i) & kk) == 0);
                    ull a = skey[i], c = skey[ixj];
                    bool sw = up ? (a < c) : (a > c);
                    if (sw) {
                        skey[i] = c; skey[ixj] = a;
                        uint tp = spay[i]; spay[i] = spay[ixj]; spay[ixj] = tp;
                    }
                }
            }
            __syncthreads();
        }
    }
    for (int i = tid; i < NW; i += 1024) svm[i] = 0ull;
    __syncthreads();
    for (int i = tid; i < KSEL; i += 1024) {
        uint slot = spay[i];
        sortedSlot[b * KSEL + i] = (int)slot;
        int v = selValid[b * KSEL + slot];
        if (v) atomicOr(&svm[i >> 6], 1ull << (i & 63));
        int lvl = (int)slot / 1000;
        float off = 1217.0f * (float)lvl;
        float4 bx = *(const float4*)&selBox[((size_t)b * KSEL + slot) * 4];
        bx.x += off; bx.y += off; bx.z += off; bx.w += off;
        *(float4*)&sortedBoxOff[((size_t)b * KSEL + i) * 4] = bx;
    }
    __syncthreads();
    for (int i = tid; i < NW; i += 1024) validMask[b * NW + i] = svm[i];
}

// ---------------- NMS pairwise suppression bitmask (upper-triangle launch) ----------------
__global__ __launch_bounds__(64) void nms_mask(const float* __restrict__ sortedBoxOff,
                                               ull* __restrict__ mat)
{
    const int b = blockIdx.y;
    const int tid = threadIdx.x;
    int rem = blockIdx.x, ib = 0;
    while (rem >= NW - ib) { rem -= NW - ib; ++ib; }
    const int jb = ib + rem;

    __shared__ float4 bj[64];
    __shared__ float  aj[64];
    const int j0 = jb * 64;
    const int jn = (KSEL - j0) < 64 ? (KSEL - j0) : 64;
    if (tid < jn) {
        float4 v = *(const float4*)&sortedBoxOff[((size_t)b * KSEL + j0 + tid) * 4];
        bj[tid] = v; aj[tid] = (v.z - v.x) * (v.w - v.y);
    }
    __syncthreads();
    const int i = ib * 64 + tid;
    if (i >= KSEL) return;
    float4 bi = *(const float4*)&sortedBoxOff[((size_t)b * KSEL + i) * 4];
    float ai = (bi.z - bi.x) * (bi.w - bi.y);
    ull m = 0ull;
    for (int jj = 0; jj < jn; ++jj) {
        int j = j0 + jj;
        if (j <= i) continue;
        float4 bb = bj[jj];
        float ltx = fmaxf(bi.x, bb.x), lty = fmaxf(bi.y, bb.y);
        float rbx = fminf(bi.z, bb.z), rby = fminf(bi.w, bb.w);
        float wx = fmaxf(rbx - ltx, 0.f), wy = fmaxf(rby - lty, 0.f);
        float inter = wx * wy;
        float iou = inter / (ai + aj[jj] - inter + 1e-9f);
        if (iou > 0.7f) m |= (1ull << jj);
    }
    mat[((size_t)b * KSEL + i) * NW + jb] = m;
}

// ---------------- greedy scan (1 wave/batch, double-buffered 16-row prefetch) ----------------
#define LOADG(RA, RB, G) { int base0 = (G) * 16; \
    _Pragma("unroll") for (int d = 0; d < 16; ++d) { int i = base0 + d; \
        RA[d] = (i < KSEL) ? mb[(size_t)i * NW + lane] : 0ull; \
        RB[d] = (hasHi && i < KSEL) ? mb[(size_t)i * NW + 64 + lane] : 0ull; } }
#define PROCG(RA, RB, G) { int base0 = (G) * 16; \
    _Pragma("unroll") for (int d = 0; d < 16; ++d) { int i = base0 + d; \
        if (i < KSEL) { int wi = i >> 6; \
            ull act0 = v0 & ~s0, act1 = v1 & ~s1; \
            ull aw = (wi < 64) ? __shfl(act0, wi, 64) : __shfl(act1, wi - 64, 64); \
            if ((aw >> (i & 63)) & 1ull) { \
                s0 |= (lane >= wi) ? RA[d] : 0ull; \
                s1 |= (lane + 64 >= wi) ? RB[d] : 0ull; \
                if (lane == 0) keptPos[b * POST_NMS + nk] = i; \
                ++nk; \
                if (nk == POST_NMS) { if (lane == 0) nkOut[b] = nk; return; } } } } }

__global__ __launch_bounds__(64) void nms_scan(const ull* __restrict__ mat,
                                               const ull* __restrict__ validMask,
                                               int* __restrict__ keptPos,
                                               int* __restrict__ nkOut)
{
    const int b = blockIdx.x, lane = threadIdx.x;
    const bool hasHi = lane < NW - 64;
    ull v0 = validMask[b * NW + lane];
    ull v1 = hasHi ? validMask[b * NW + 64 + lane] : 0ull;
    ull s0 = 0ull, s1 = 0ull;
    int nk = 0;
    const ull* mb = mat + (size_t)b * KSEL * NW;
    const int NG = (KSEL + 15) / 16;   // 297

    ull A0[16], B0[16], A1[16], B1[16];
    LOADG(A0, B0, 0);
    for (int g = 0; g < NG; g += 2) {
        if (g + 1 < NG) LOADG(A1, B1, g + 1);
        PROCG(A0, B0, g);
        if (g + 2 < NG) LOADG(A0, B0, g + 2);
        if (g + 1 < NG) PROCG(A1, B1, g + 1);
    }
    if (lane == 0) nkOut[b] = nk;
}

// ---------------- final output ----------------
__global__ __launch_bounds__(256) void out_kernel(
    const int* __restrict__ keptPos, const int* __restrict__ nkOut,
    const int* __restrict__ sortedSlot,
    const float* __restrict__ selBox, const float* __restrict__ selScore,
    float* __restrict__ out)
{
    int t = blockIdx.x * 256 + threadIdx.x;
    if (t >= BATCH * POST_NMS) return;
    int b = t / POST_NMS, row = t - b * POST_NMS;
    float4 bx = make_float4(0.f, 0.f, 0.f, 0.f);
    float sc = -1e9f;
    if (row < nkOut[b]) {
        int i = keptPos[b * POST_NMS + row];
        int slot = sortedSlot[b * KSEL + i];
        bx = *(const float4*)&selBox[((size_t)b * KSEL + slot) * 4];
        sc = selScore[b * KSEL + slot];
    }
    *(float4*)&out[(size_t)t * 4] = bx;
    out[BATCH * POST_NMS * 4 + t] = sc;
}

// ---------------- host launch ----------------
extern "C" void kernel_launch(void* const* d_in, const int* in_sizes, int n_in,
                              void* d_out, int out_size, void* d_ws, size_t ws_size,
                              hipStream_t stream)
{
    (void)in_sizes; (void)n_in; (void)out_size; (void)ws_size;
    const float* feat[5] = {(const float*)d_in[0], (const float*)d_in[1],
                            (const float*)d_in[2], (const float*)d_in[3],
                            (const float*)d_in[4]};
    const float* conv_w = (const float*)d_in[5];
    const float* conv_b = (const float*)d_in[6];
    const float* cls_w  = (const float*)d_in[7];
    const float* cls_b  = (const float*)d_in[8];
    const float* box_w  = (const float*)d_in[9];
    const float* box_b  = (const float*)d_in[10];
    float* out = (float*)d_out;

    char* ws = (char*)d_ws;
    size_t off = 0;
    auto carve = [&](size_t bytes) -> void* {
        void* p = (void*)(ws + off);
        off += (bytes + 255) & ~(size_t)255;
        return p;
    };
    ushort* wB         = (ushort*)carve((size_t)WB_ELEMS * 2);
    float* scoresA     = (float*)carve((size_t)BATCH * ATOTAL * 4);
    float* boxesA      = (float*)carve((size_t)BATCH * ATOTAL * 16);
    float* selScore    = (float*)carve((size_t)BATCH * KSEL * 4);
    float* selBox      = (float*)carve((size_t)BATCH * KSEL * 16);
    int*   selValid    = (int*)  carve((size_t)BATCH * KSEL * 4);
    int*   selAnchor   = (int*)  carve((size_t)BATCH * KSEL * 4);
    int*   sortedSlot  = (int*)  carve((size_t)BATCH * KSEL * 4);
    float* sortedBoxOff= (float*)carve((size_t)BATCH * KSEL * 16);
    ull*   validMask   = (ull*)  carve((size_t)BATCH * NW * 8);
    ull*   mat         = (ull*)  carve((size_t)BATCH * KSEL * NW * 8);
    int*   keptPos     = (int*)  carve((size_t)BATCH * POST_NMS * 4);
    int*   nkOut       = (int*)  carve(64);

    wt_kernel<<<(WB_ELEMS + 255) / 256, 256, 0, stream>>>(conv_w, wB);

    conv_mfma_all<<<dim3(656, BATCH), 512, 0, stream>>>(
        feat[0], feat[1], feat[2], feat[3], feat[4], wB, conv_b,
        cls_w, cls_b, box_w, box_b, scoresA, boxesA);

    topk_kernel<<<dim3(5, BATCH), 1024, 0, stream>>>(scoresA, boxesA, selScore, selBox, selValid, selAnchor);
    sort_kernel<<<dim3(BATCH), 1024, 0, stream>>>(selScore, selBox, selValid, selAnchor, sortedSlot, sortedBoxOff, validMask);
    nms_mask<<<dim3(NPAIRS, BATCH), 64, 0, stream>>>(sortedBoxOff, mat);
    nms_scan<<<dim3(BATCH), 64, 0, stream>>>(mat, validMask, keptPos, nkOut);
    out_kernel<<<dim3((BATCH * POST_NMS + 255) / 256), 256, 0, stream>>>(keptPos, nkOut, sortedSlot, selBox, selScore, out);
}